// Round 7
// baseline (405.529 us; speedup 1.0000x reference)
//
#include <hip/hip_runtime.h>
#include <hip/hip_bf16.h>

#define FEAT 128

typedef unsigned int uint32;
typedef unsigned long long uint64;
typedef unsigned short ushort16;
typedef __attribute__((ext_vector_type(8))) short short8;
typedef __attribute__((ext_vector_type(4))) float v4f;
typedef __attribute__((ext_vector_type(2))) float f32x2;

// ---- bf16 helpers (RNE round; bf16->f32 is exact shift) ---------------------
__device__ __forceinline__ ushort16 f2bf(float f) {
    uint32 u = __float_as_uint(f);
    u += 0x7fffu + ((u >> 16) & 1u);
    return (ushort16)(u >> 16);
}
__device__ __forceinline__ float bflo(uint32 u) { return __uint_as_float(u << 16); }
__device__ __forceinline__ float bfhi(uint32 u) { return __uint_as_float(u & 0xffff0000u); }
__device__ __forceinline__ f32x2 up2(uint32 u) { return (f32x2){bflo(u), bfhi(u)}; }

// ---------------- hydra: cvt_x + hist + W01=W0@W1 (independent pre-work) -----
// blocks [0, CB): convert x fp32 -> bf16, 8 elems/thread
// blocks [CB, CB+HB): histogram of col (4 edges/thread)
// blocks [CB+HB, CB+HB+WB): W01t[n][k] = sum_j W0[k][j]*W1[j][n], fp32 acc -> bf16
__global__ __launch_bounds__(256) void hydra_kernel(const float* __restrict__ x,
                                                    ushort16* __restrict__ Xh,
                                                    const int* __restrict__ col,
                                                    int* __restrict__ counts,
                                                    const float* __restrict__ W0,
                                                    const float* __restrict__ W1,
                                                    ushort16* __restrict__ W01t,
                                                    int cvtBlocks, int histBlocks,
                                                    int total8, int E) {
    int b = blockIdx.x;
    int t = threadIdx.x;
    if (b < cvtBlocks) {
        int id = b * 256 + t;
        if (id < total8) {
            const float4 v0 = *(const float4*)(x + (size_t)id * 8);
            const float4 v1 = *(const float4*)(x + (size_t)id * 8 + 4);
            uint4 o;
            o.x = (uint32)f2bf(v0.x) | ((uint32)f2bf(v0.y) << 16);
            o.y = (uint32)f2bf(v0.z) | ((uint32)f2bf(v0.w) << 16);
            o.z = (uint32)f2bf(v1.x) | ((uint32)f2bf(v1.y) << 16);
            o.w = (uint32)f2bf(v1.z) | ((uint32)f2bf(v1.w) << 16);
            *(uint4*)(Xh + (size_t)id * 8) = o;
        }
    } else if (b < cvtBlocks + histBlocks) {
        int id = (b - cvtBlocks) * 256 + t;
        if (id * 4 + 3 < E) {
            int4 c4 = *(const int4*)(col + id * 4);
            atomicAdd(&counts[c4.x], 1);
            atomicAdd(&counts[c4.y], 1);
            atomicAdd(&counts[c4.z], 1);
            atomicAdd(&counts[c4.w], 1);
        } else {
            for (int e = id * 4; e < E; e++) atomicAdd(&counts[col[e]], 1);
        }
    } else {
        int id = (b - cvtBlocks - histBlocks) * 256 + t;  // [0, 16384)
        int ncol = id >> 7;
        int k = id & 127;
        float acc = 0.f;
        for (int j = 0; j < FEAT; j++)
            acc += W0[(size_t)k * FEAT + j] * W1[(size_t)j * FEAT + ncol];
        W01t[id] = f2bf(acc);  // layout [n][k], transposed for MFMA
    }
}

// ---------------- scan step 1: per-1024-chunk sums ---------------------------
__global__ __launch_bounds__(256) void scan_part(const int* __restrict__ counts,
                                                 int* __restrict__ bsum, int n) {
    __shared__ int s[256];
    int base = blockIdx.x * 1024;
    int t = threadIdx.x;
    int v = 0;
#pragma unroll
    for (int i = 0; i < 4; i++) {
        int idx = base + t * 4 + i;
        if (idx < n) v += counts[idx];
    }
    s[t] = v;
    __syncthreads();
    for (int o = 128; o > 0; o >>= 1) {
        if (t < o) s[t] += s[t + o];
        __syncthreads();
    }
    if (t == 0) bsum[blockIdx.x] = s[0];
}

// ---------------- scan step 2: exclusive scan of block sums (nb <= 128) ------
__global__ void scan_bsum(int* __restrict__ bsum, int nb) {
    __shared__ int s[128];
    int t = threadIdx.x;
    int v0 = (t < nb) ? bsum[t] : 0;
    s[t] = v0;
    __syncthreads();
    for (int o = 1; o < 128; o <<= 1) {
        int v = (t >= o) ? s[t - o] : 0;
        __syncthreads();
        s[t] += v;
        __syncthreads();
    }
    if (t < nb) bsum[t] = s[t] - v0;  // exclusive
}

// ---------------- scan step 3: final offsets + next[] + dinv -----------------
__global__ __launch_bounds__(256) void scan_final(const int* __restrict__ counts,
                                                  const int* __restrict__ bsum,
                                                  int* __restrict__ off, int* __restrict__ nxt,
                                                  float* __restrict__ dinv, int n) {
    __shared__ int s[256];
    int base = blockIdx.x * 1024;
    int t = threadIdx.x;
    int c[4];
    int sum = 0;
#pragma unroll
    for (int i = 0; i < 4; i++) {
        int idx = base + t * 4 + i;
        c[i] = (idx < n) ? counts[idx] : 0;
        sum += c[i];
    }
    int v0 = sum;
    s[t] = sum;
    __syncthreads();
    for (int o = 1; o < 256; o <<= 1) {
        int v = (t >= o) ? s[t - o] : 0;
        __syncthreads();
        s[t] += v;
        __syncthreads();
    }
    int excl = s[t] - v0 + bsum[blockIdx.x];
#pragma unroll
    for (int i = 0; i < 4; i++) {
        int idx = base + t * 4 + i;
        if (idx < n) {
            off[idx] = excl;
            nxt[idx] = excl;
            dinv[idx] = rsqrtf((float)(c[i] + 1));  // +1 = self loop
        }
        excl += c[i];
    }
    if (blockIdx.x == gridDim.x - 1 && t == 255) off[n] = excl;  // == E
}

// ---------------- CSR fill: edge record (src, dinv[src]) as nt uint64 --------
// nontemporal store: R6 showed 44MB WRITE_SIZE (write-allocate thrash of the
// scattered 8B stores over the 5MB erec region); nt bypasses the allocate.
__global__ void fill_kernel(const int* __restrict__ row, const int* __restrict__ col,
                            const float* __restrict__ dinv, int* __restrict__ nxt,
                            uint64* __restrict__ erec, int E) {
    int e = blockIdx.x * 256 + threadIdx.x;
    if (e < E) {
        int c = col[e], r = row[e];
        int p = atomicAdd(&nxt[c], 1);
        uint64 v = (uint64)(uint32)r | ((uint64)__float_as_uint(dinv[r]) << 32);
        __builtin_nontemporal_store(v, &erec[p]);
    }
}

// ---------------- bf16 MFMA GEMM: Ch = bf16(leaky?(Ah @ W)), W transposed ----
// One instance left (linearity folded the other two away). Half-W-per-wave
// register-resident design (R6): wave owns 64 cols of W (16 short8 = 64 VGPR),
// wave pairs cover a 16-row tile, A software-prefetched, no LDS, no barriers.
// OPERAND SWAP (verified R4): mfma(Wfrag, Afrag) -> lane holds 4 consecutive
// W-cols (quad*4+reg) of node row l16 -> direct 8B packed stores.
__global__ __launch_bounds__(256) void gemm_mfma(const ushort16* __restrict__ A,
                                                 const ushort16* __restrict__ Wt,
                                                 ushort16* __restrict__ Ch, int n,
                                                 int leaky) {
    const int t = threadIdx.x;
    const int w = t >> 6;
    const int lane = t & 63;
    const int quad = lane >> 4;
    const int l16 = lane & 15;
    const int colBase = (w & 1) * 64;

    short8 wf[4][4];
#pragma unroll
    for (int ct = 0; ct < 4; ct++) {
        const ushort16* wp = Wt + (size_t)(colBase + ct * 16 + l16) * FEAT + quad * 8;
#pragma unroll
        for (int ks = 0; ks < 4; ks++) wf[ct][ks] = *(const short8*)(wp + ks * 32);
    }

    const int nTiles = (n + 15) >> 4;
    const int tStride = gridDim.x * 2;
    int tile = blockIdx.x * 2 + (w >> 1);
    if (tile >= nTiles) return;

    auto loadA = [&](int tl, short8 (&a)[4]) {
        const int row = tl * 16 + l16;
        if (row < n) {
            const ushort16* ap = A + (size_t)row * FEAT + quad * 8;
#pragma unroll
            for (int ks = 0; ks < 4; ks++) a[ks] = *(const short8*)(ap + ks * 32);
        } else {
#pragma unroll
            for (int ks = 0; ks < 4; ks++) a[ks] = (short8)0;
        }
    };

    short8 aCur[4];
    loadA(tile, aCur);

    while (tile < nTiles) {
        const int nextTile = tile + tStride;
        short8 aNxt[4];
        if (nextTile < nTiles) loadA(nextTile, aNxt);

        v4f acc[4];
#pragma unroll
        for (int ct = 0; ct < 4; ct++) acc[ct] = (v4f)0.f;
#pragma unroll
        for (int ct = 0; ct < 4; ct++)
#pragma unroll
            for (int ks = 0; ks < 4; ks++)
                acc[ct] = __builtin_amdgcn_mfma_f32_16x16x32_bf16(wf[ct][ks], aCur[ks], acc[ct], 0, 0, 0);

        const int row = tile * 16 + l16;
        if (row < n) {
#pragma unroll
            for (int ct = 0; ct < 4; ct++) {
                float p0 = acc[ct][0], p1 = acc[ct][1], p2 = acc[ct][2], p3 = acc[ct][3];
                if (leaky) {
                    p0 = (p0 >= 0.f) ? p0 : 0.01f * p0;
                    p1 = (p1 >= 0.f) ? p1 : 0.01f * p1;
                    p2 = (p2 >= 0.f) ? p2 : 0.01f * p2;
                    p3 = (p3 >= 0.f) ? p3 : 0.01f * p3;
                }
                uint2 o;
                o.x = (uint32)f2bf(p0) | ((uint32)f2bf(p1) << 16);
                o.y = (uint32)f2bf(p2) | ((uint32)f2bf(p3) << 16);
                *(uint2*)(Ch + (size_t)row * FEAT + colBase + ct * 16 + quad * 4) = o;
            }
        }

        tile = nextTile;
#pragma unroll
        for (int ks = 0; ks < 4; ks++) aCur[ks] = aNxt[ks];
    }
}

// ---------------- gather-propagate over bf16 table ---------------------------
// H[c] = dinv[c]^2*T[c] + sum_e dinv[c]*dinv[src_e]*T[src_e]; bf16 out.
// 4 edge-groups x 16 lanes x 16B, unroll-2 (R5 structure; pinned ~49us by
// L2-miss traffic at L3 random rate -- structural).
__global__ __launch_bounds__(256) void gather_kernel(const int* __restrict__ off,
                                                     const uint2* __restrict__ erec,
                                                     const float* __restrict__ dinv,
                                                     const ushort16* __restrict__ XWh,
                                                     ushort16* __restrict__ Hh, int n) {
    int node = blockIdx.x * 4 + (threadIdx.x >> 6);
    if (node >= n) return;
    int lane = threadIdx.x & 63;
    int grp = lane >> 4;
    int l16 = lane & 15;
    float dc = dinv[node];
    const uint4* table = (const uint4*)XWh;

    f32x2 acc[4];
    if (grp == 0) {  // self-loop term
        uint4 v = table[(size_t)node * 16 + l16];
        f32x2 w0 = (f32x2){dc * dc, dc * dc};
        acc[0] = w0 * up2(v.x);
        acc[1] = w0 * up2(v.y);
        acc[2] = w0 * up2(v.z);
        acc[3] = w0 * up2(v.w);
    } else {
#pragma unroll
        for (int j = 0; j < 4; j++) acc[j] = (f32x2){0.f, 0.f};
    }

    int s = off[node], e = off[node + 1];
    int i = s + grp;
    for (; i + 4 < e; i += 8) {
        uint2 er0 = erec[i];
        uint2 er1 = erec[i + 4];
        uint4 u0 = table[(size_t)er0.x * 16 + l16];
        uint4 u1 = table[(size_t)er1.x * 16 + l16];
        float f0 = dc * __uint_as_float(er0.y);
        float f1 = dc * __uint_as_float(er1.y);
        f32x2 n0 = (f32x2){f0, f0};
        f32x2 n1 = (f32x2){f1, f1};
        acc[0] += n0 * up2(u0.x);
        acc[1] += n0 * up2(u0.y);
        acc[2] += n0 * up2(u0.z);
        acc[3] += n0 * up2(u0.w);
        acc[0] += n1 * up2(u1.x);
        acc[1] += n1 * up2(u1.y);
        acc[2] += n1 * up2(u1.z);
        acc[3] += n1 * up2(u1.w);
    }
    if (i < e) {
        uint2 er0 = erec[i];
        uint4 u0 = table[(size_t)er0.x * 16 + l16];
        float f0 = dc * __uint_as_float(er0.y);
        f32x2 n0 = (f32x2){f0, f0};
        acc[0] += n0 * up2(u0.x);
        acc[1] += n0 * up2(u0.y);
        acc[2] += n0 * up2(u0.z);
        acc[3] += n0 * up2(u0.w);
    }

    float b[8] = {acc[0].x, acc[0].y, acc[1].x, acc[1].y,
                  acc[2].x, acc[2].y, acc[3].x, acc[3].y};
#pragma unroll
    for (int j = 0; j < 8; j++) {
        b[j] += __shfl_xor(b[j], 16);
        b[j] += __shfl_xor(b[j], 32);
    }

    if (grp == 0) {
        uint4 o;
        o.x = (uint32)f2bf(b[0]) | ((uint32)f2bf(b[1]) << 16);
        o.y = (uint32)f2bf(b[2]) | ((uint32)f2bf(b[3]) << 16);
        o.z = (uint32)f2bf(b[4]) | ((uint32)f2bf(b[5]) << 16);
        o.w = (uint32)f2bf(b[6]) | ((uint32)f2bf(b[7]) << 16);
        *(uint4*)(Hh + (size_t)node * FEAT + l16 * 8) = o;
    }
}

// ---------------- pool + final GEMM: out[g] = (sum_{i in g} G3[i]) @ W2 ------
// pool(A(H3 W2)) == pool(A H3) @ W2 by linearity -> the 100K-row layer-2 GEMM
// becomes a 512-row fp32 one, fused here. batch is sorted: block g binary-
// searches its node range; no atomics, no zero-init of out.
__global__ __launch_bounds__(128) void poolgemm_kernel(const ushort16* __restrict__ G3h,
                                                       const int* __restrict__ batch,
                                                       const float* __restrict__ W2,
                                                       float* __restrict__ out, int n) {
    __shared__ float P[FEAT];
    const int g = blockIdx.x;
    const int t = threadIdx.x;

    // lower_bound(batch, g) and lower_bound(batch, g+1)
    int lo = 0, hi = n;
    while (lo < hi) { int m = (lo + hi) >> 1; if (batch[m] < g) lo = m + 1; else hi = m; }
    int s = lo;
    hi = n;
    while (lo < hi) { int m = (lo + hi) >> 1; if (batch[m] < g + 1) lo = m + 1; else hi = m; }
    int e = lo;

    float acc = 0.f;
    for (int i = s; i < e; i++) {
        uint32 u = (uint32)(unsigned short)G3h[(size_t)i * FEAT + t];
        acc += __uint_as_float(u << 16);
    }
    P[t] = acc;
    __syncthreads();

    float o = 0.f;
    for (int k = 0; k < FEAT; k++) o += P[k] * W2[(size_t)k * FEAT + t];
    out[(size_t)g * FEAT + t] = o;
}

extern "C" void kernel_launch(void* const* d_in, const int* in_sizes, int n_in,
                              void* d_out, int out_size, void* d_ws, size_t ws_size,
                              hipStream_t stream) {
    const float* x = (const float*)d_in[0];
    const int* ei = (const int*)d_in[1];
    const int* batch = (const int*)d_in[2];
    const float* W0 = (const float*)d_in[3];
    const float* W1 = (const float*)d_in[4];
    const float* W2 = (const float*)d_in[5];
    float* out = (float*)d_out;

    const int N = in_sizes[0] / FEAT;  // 100000
    const int E = in_sizes[1] / 2;     // 640000
    const int G = out_size / FEAT;     // 512

    const int* rowI = ei;
    const int* colI = ei + E;

    char* ws = (char*)d_ws;
    auto take = [&](size_t bytes) {
        char* p = ws;
        ws += (bytes + 15) & ~(size_t)15;
        return p;
    };
    int* counts    = (int*)take((size_t)N * 4);
    int* off       = (int*)take((size_t)(N + 1) * 4);
    int* nxt       = (int*)take((size_t)N * 4);
    float* dinv    = (float*)take((size_t)N * 4);
    int* bsum      = (int*)take(128 * 4);
    uint64* erec   = (uint64*)take((size_t)E * 8);
    ushort16* W01t = (ushort16*)take((size_t)16384 * 2);
    ushort16* Xh   = (ushort16*)take((size_t)N * FEAT * 2);
    ushort16* bufA = (ushort16*)take((size_t)N * FEAT * 2);
    ushort16* bufB = (ushort16*)take((size_t)N * FEAT * 2);

    const int nb = (N + 1023) / 1024;
    const int eb = (E + 255) / 256;

    // ---- zero counts, then fused pre-work (cvt_x + hist + W01) ----
    hipMemsetAsync(counts, 0, (size_t)N * 4, stream);
    const int total8 = N * FEAT / 8;
    const int cvtBlocks = (total8 + 255) / 256;
    const int histBlocks = (E + 1023) / 1024;
    const int w01Blocks = 16384 / 256;
    hydra_kernel<<<cvtBlocks + histBlocks + w01Blocks, 256, 0, stream>>>(
        x, Xh, colI, counts, W0, W1, W01t, cvtBlocks, histBlocks, total8, E);

    // ---- CSR build ----
    scan_part<<<nb, 256, 0, stream>>>(counts, bsum, N);
    scan_bsum<<<1, 128, 0, stream>>>(bsum, nb);
    scan_final<<<nb, 256, 0, stream>>>(counts, bsum, off, nxt, dinv, N);
    fill_kernel<<<eb, 256, 0, stream>>>(rowI, colI, dinv, nxt, erec, E);

    const int gatBlocks = (N + 3) / 4;

    // ---- H2 = A A X (W0 W1), leaky -> H3 ----
    gather_kernel<<<gatBlocks, 256, 0, stream>>>(off, (const uint2*)erec, dinv, Xh, bufA, N);
    gather_kernel<<<gatBlocks, 256, 0, stream>>>(off, (const uint2*)erec, dinv, bufA, bufB, N);
    gemm_mfma<<<1024, 256, 0, stream>>>(bufB, W01t, bufA, N, 1);  // leaky fused
    // ---- G3 = A H3 ----
    gather_kernel<<<gatBlocks, 256, 0, stream>>>(off, (const uint2*)erec, dinv, bufA, bufB, N);
    // ---- out = pool(G3) @ W2 ----
    poolgemm_kernel<<<G, 128, 0, stream>>>(bufB, batch, W2, out, N);
}

// Round 8
// 373.631 us; speedup vs baseline: 1.0854x; 1.0854x over previous
//
#include <hip/hip_runtime.h>
#include <hip/hip_bf16.h>

#define FEAT 128

typedef unsigned int uint32;
typedef unsigned long long uint64;
typedef unsigned short ushort16;
typedef __attribute__((ext_vector_type(8))) short short8;
typedef __attribute__((ext_vector_type(4))) float v4f;
typedef __attribute__((ext_vector_type(2))) float f32x2;

// ---- bf16 helpers (RNE round; bf16->f32 is exact shift) ---------------------
__device__ __forceinline__ ushort16 f2bf(float f) {
    uint32 u = __float_as_uint(f);
    u += 0x7fffu + ((u >> 16) & 1u);
    return (ushort16)(u >> 16);
}
__device__ __forceinline__ float bflo(uint32 u) { return __uint_as_float(u << 16); }
__device__ __forceinline__ float bfhi(uint32 u) { return __uint_as_float(u & 0xffff0000u); }
__device__ __forceinline__ f32x2 up2(uint32 u) { return (f32x2){bflo(u), bfhi(u)}; }

// ---------------- hydra: cvt_x + hist + W01=W0@W1 (independent pre-work) -----
// blocks [0, CB): convert x fp32 -> bf16, 8 elems/thread
// blocks [CB, CB+HB): histogram of col (4 edges/thread)
// blocks [CB+HB, CB+HB+64): W01t[n][k] = sum_j W0[k][j]*W1[j][n].
//   2 k-rows/block staged in LDS; W1 row reads coalesced across lanes
//   (R7 version: 256 serial strided loads/thread -> latency-bound straggler).
__global__ __launch_bounds__(256) void hydra_kernel(const float* __restrict__ x,
                                                    ushort16* __restrict__ Xh,
                                                    const int* __restrict__ col,
                                                    int* __restrict__ counts,
                                                    const float* __restrict__ W0,
                                                    const float* __restrict__ W1,
                                                    ushort16* __restrict__ W01t,
                                                    int cvtBlocks, int histBlocks,
                                                    int total8, int E) {
    int b = blockIdx.x;
    int t = threadIdx.x;
    if (b < cvtBlocks) {
        int id = b * 256 + t;
        if (id < total8) {
            const float4 v0 = *(const float4*)(x + (size_t)id * 8);
            const float4 v1 = *(const float4*)(x + (size_t)id * 8 + 4);
            uint4 o;
            o.x = (uint32)f2bf(v0.x) | ((uint32)f2bf(v0.y) << 16);
            o.y = (uint32)f2bf(v0.z) | ((uint32)f2bf(v0.w) << 16);
            o.z = (uint32)f2bf(v1.x) | ((uint32)f2bf(v1.y) << 16);
            o.w = (uint32)f2bf(v1.z) | ((uint32)f2bf(v1.w) << 16);
            *(uint4*)(Xh + (size_t)id * 8) = o;
        }
    } else if (b < cvtBlocks + histBlocks) {
        int id = (b - cvtBlocks) * 256 + t;
        if (id * 4 + 3 < E) {
            int4 c4 = *(const int4*)(col + id * 4);
            atomicAdd(&counts[c4.x], 1);
            atomicAdd(&counts[c4.y], 1);
            atomicAdd(&counts[c4.z], 1);
            atomicAdd(&counts[c4.w], 1);
        } else {
            for (int e = id * 4; e < E; e++) atomicAdd(&counts[col[e]], 1);
        }
    } else {
        __shared__ float sW0[2][FEAT];
        int wb = b - cvtBlocks - histBlocks;  // [0, 64)
        int lk = t >> 7;                      // which of the 2 k-rows
        int ncol = t & 127;
        int k = wb * 2 + lk;
        sW0[lk][ncol] = W0[(size_t)k * FEAT + ncol];
        __syncthreads();
        float acc = 0.f;
#pragma unroll 4
        for (int j = 0; j < FEAT; j++)
            acc += sW0[lk][j] * W1[(size_t)j * FEAT + ncol];  // coalesced across lanes
        W01t[(size_t)ncol * FEAT + k] = f2bf(acc);  // [n][k], transposed for MFMA
    }
}

// ---------------- scan step 1: per-1024-chunk sums ---------------------------
__global__ __launch_bounds__(256) void scan_part(const int* __restrict__ counts,
                                                 int* __restrict__ bsum, int n) {
    __shared__ int s[256];
    int base = blockIdx.x * 1024;
    int t = threadIdx.x;
    int v = 0;
#pragma unroll
    for (int i = 0; i < 4; i++) {
        int idx = base + t * 4 + i;
        if (idx < n) v += counts[idx];
    }
    s[t] = v;
    __syncthreads();
    for (int o = 128; o > 0; o >>= 1) {
        if (t < o) s[t] += s[t + o];
        __syncthreads();
    }
    if (t == 0) bsum[blockIdx.x] = s[0];
}

// ---------------- scan step 2: exclusive scan of block sums (nb <= 128) ------
__global__ void scan_bsum(int* __restrict__ bsum, int nb) {
    __shared__ int s[128];
    int t = threadIdx.x;
    int v0 = (t < nb) ? bsum[t] : 0;
    s[t] = v0;
    __syncthreads();
    for (int o = 1; o < 128; o <<= 1) {
        int v = (t >= o) ? s[t - o] : 0;
        __syncthreads();
        s[t] += v;
        __syncthreads();
    }
    if (t < nb) bsum[t] = s[t] - v0;  // exclusive
}

// ---------------- scan step 3: final offsets + next[] + dinv -----------------
__global__ __launch_bounds__(256) void scan_final(const int* __restrict__ counts,
                                                  const int* __restrict__ bsum,
                                                  int* __restrict__ off, int* __restrict__ nxt,
                                                  float* __restrict__ dinv, int n) {
    __shared__ int s[256];
    int base = blockIdx.x * 1024;
    int t = threadIdx.x;
    int c[4];
    int sum = 0;
#pragma unroll
    for (int i = 0; i < 4; i++) {
        int idx = base + t * 4 + i;
        c[i] = (idx < n) ? counts[idx] : 0;
        sum += c[i];
    }
    int v0 = sum;
    s[t] = sum;
    __syncthreads();
    for (int o = 1; o < 256; o <<= 1) {
        int v = (t >= o) ? s[t - o] : 0;
        __syncthreads();
        s[t] += v;
        __syncthreads();
    }
    int excl = s[t] - v0 + bsum[blockIdx.x];
#pragma unroll
    for (int i = 0; i < 4; i++) {
        int idx = base + t * 4 + i;
        if (idx < n) {
            off[idx] = excl;
            nxt[idx] = excl;
            dinv[idx] = rsqrtf((float)(c[i] + 1));  // +1 = self loop
        }
        excl += c[i];
    }
    if (blockIdx.x == gridDim.x - 1 && t == 255) off[n] = excl;  // == E
}

// ---------------- CSR fill: edge record (src, dinv[src]) as nt uint64 --------
__global__ void fill_kernel(const int* __restrict__ row, const int* __restrict__ col,
                            const float* __restrict__ dinv, int* __restrict__ nxt,
                            uint64* __restrict__ erec, int E) {
    int e = blockIdx.x * 256 + threadIdx.x;
    if (e < E) {
        int c = col[e], r = row[e];
        int p = atomicAdd(&nxt[c], 1);
        uint64 v = (uint64)(uint32)r | ((uint64)__float_as_uint(dinv[r]) << 32);
        __builtin_nontemporal_store(v, &erec[p]);
    }
}

// ---------------- bf16 MFMA GEMM: Ch = bf16(leaky?(Ah @ W)), W transposed ----
// Half-W-per-wave register-resident (R6 design, frozen). OPERAND SWAP
// (verified R4): mfma(Wfrag, Afrag) -> lane holds 4 consecutive W-cols of
// node row l16 -> direct 8B packed stores.
__global__ __launch_bounds__(256) void gemm_mfma(const ushort16* __restrict__ A,
                                                 const ushort16* __restrict__ Wt,
                                                 ushort16* __restrict__ Ch, int n,
                                                 int leaky) {
    const int t = threadIdx.x;
    const int w = t >> 6;
    const int lane = t & 63;
    const int quad = lane >> 4;
    const int l16 = lane & 15;
    const int colBase = (w & 1) * 64;

    short8 wf[4][4];
#pragma unroll
    for (int ct = 0; ct < 4; ct++) {
        const ushort16* wp = Wt + (size_t)(colBase + ct * 16 + l16) * FEAT + quad * 8;
#pragma unroll
        for (int ks = 0; ks < 4; ks++) wf[ct][ks] = *(const short8*)(wp + ks * 32);
    }

    const int nTiles = (n + 15) >> 4;
    const int tStride = gridDim.x * 2;
    int tile = blockIdx.x * 2 + (w >> 1);
    if (tile >= nTiles) return;

    auto loadA = [&](int tl, short8 (&a)[4]) {
        const int row = tl * 16 + l16;
        if (row < n) {
            const ushort16* ap = A + (size_t)row * FEAT + quad * 8;
#pragma unroll
            for (int ks = 0; ks < 4; ks++) a[ks] = *(const short8*)(ap + ks * 32);
        } else {
#pragma unroll
            for (int ks = 0; ks < 4; ks++) a[ks] = (short8)0;
        }
    };

    short8 aCur[4];
    loadA(tile, aCur);

    while (tile < nTiles) {
        const int nextTile = tile + tStride;
        short8 aNxt[4];
        if (nextTile < nTiles) loadA(nextTile, aNxt);

        v4f acc[4];
#pragma unroll
        for (int ct = 0; ct < 4; ct++) acc[ct] = (v4f)0.f;
#pragma unroll
        for (int ct = 0; ct < 4; ct++)
#pragma unroll
            for (int ks = 0; ks < 4; ks++)
                acc[ct] = __builtin_amdgcn_mfma_f32_16x16x32_bf16(wf[ct][ks], aCur[ks], acc[ct], 0, 0, 0);

        const int row = tile * 16 + l16;
        if (row < n) {
#pragma unroll
            for (int ct = 0; ct < 4; ct++) {
                float p0 = acc[ct][0], p1 = acc[ct][1], p2 = acc[ct][2], p3 = acc[ct][3];
                if (leaky) {
                    p0 = (p0 >= 0.f) ? p0 : 0.01f * p0;
                    p1 = (p1 >= 0.f) ? p1 : 0.01f * p1;
                    p2 = (p2 >= 0.f) ? p2 : 0.01f * p2;
                    p3 = (p3 >= 0.f) ? p3 : 0.01f * p3;
                }
                uint2 o;
                o.x = (uint32)f2bf(p0) | ((uint32)f2bf(p1) << 16);
                o.y = (uint32)f2bf(p2) | ((uint32)f2bf(p3) << 16);
                *(uint2*)(Ch + (size_t)row * FEAT + colBase + ct * 16 + quad * 4) = o;
            }
        }

        tile = nextTile;
#pragma unroll
        for (int ks = 0; ks < 4; ks++) aCur[ks] = aNxt[ks];
    }
}

// ---------------- gather-propagate over bf16 table ---------------------------
// H[c] = dinv[c]^2*T[c] + sum_e dinv[c]*dinv[src_e]*T[src_e]; bf16 out.
// 4 edge-groups x 16 lanes x 16B, unroll-2 (structural ~49us: L2-miss traffic
// at L3 random-access rate; R3/R4/R5 variants all equal).
__global__ __launch_bounds__(256) void gather_kernel(const int* __restrict__ off,
                                                     const uint2* __restrict__ erec,
                                                     const float* __restrict__ dinv,
                                                     const ushort16* __restrict__ XWh,
                                                     ushort16* __restrict__ Hh, int n) {
    int node = blockIdx.x * 4 + (threadIdx.x >> 6);
    if (node >= n) return;
    int lane = threadIdx.x & 63;
    int grp = lane >> 4;
    int l16 = lane & 15;
    float dc = dinv[node];
    const uint4* table = (const uint4*)XWh;

    f32x2 acc[4];
    if (grp == 0) {  // self-loop term
        uint4 v = table[(size_t)node * 16 + l16];
        f32x2 w0 = (f32x2){dc * dc, dc * dc};
        acc[0] = w0 * up2(v.x);
        acc[1] = w0 * up2(v.y);
        acc[2] = w0 * up2(v.z);
        acc[3] = w0 * up2(v.w);
    } else {
#pragma unroll
        for (int j = 0; j < 4; j++) acc[j] = (f32x2){0.f, 0.f};
    }

    int s = off[node], e = off[node + 1];
    int i = s + grp;
    for (; i + 4 < e; i += 8) {
        uint2 er0 = erec[i];
        uint2 er1 = erec[i + 4];
        uint4 u0 = table[(size_t)er0.x * 16 + l16];
        uint4 u1 = table[(size_t)er1.x * 16 + l16];
        float f0 = dc * __uint_as_float(er0.y);
        float f1 = dc * __uint_as_float(er1.y);
        f32x2 n0 = (f32x2){f0, f0};
        f32x2 n1 = (f32x2){f1, f1};
        acc[0] += n0 * up2(u0.x);
        acc[1] += n0 * up2(u0.y);
        acc[2] += n0 * up2(u0.z);
        acc[3] += n0 * up2(u0.w);
        acc[0] += n1 * up2(u1.x);
        acc[1] += n1 * up2(u1.y);
        acc[2] += n1 * up2(u1.z);
        acc[3] += n1 * up2(u1.w);
    }
    if (i < e) {
        uint2 er0 = erec[i];
        uint4 u0 = table[(size_t)er0.x * 16 + l16];
        float f0 = dc * __uint_as_float(er0.y);
        f32x2 n0 = (f32x2){f0, f0};
        acc[0] += n0 * up2(u0.x);
        acc[1] += n0 * up2(u0.y);
        acc[2] += n0 * up2(u0.z);
        acc[3] += n0 * up2(u0.w);
    }

    float b[8] = {acc[0].x, acc[0].y, acc[1].x, acc[1].y,
                  acc[2].x, acc[2].y, acc[3].x, acc[3].y};
#pragma unroll
    for (int j = 0; j < 8; j++) {
        b[j] += __shfl_xor(b[j], 16);
        b[j] += __shfl_xor(b[j], 32);
    }

    if (grp == 0) {
        uint4 o;
        o.x = (uint32)f2bf(b[0]) | ((uint32)f2bf(b[1]) << 16);
        o.y = (uint32)f2bf(b[2]) | ((uint32)f2bf(b[3]) << 16);
        o.z = (uint32)f2bf(b[4]) | ((uint32)f2bf(b[5]) << 16);
        o.w = (uint32)f2bf(b[6]) | ((uint32)f2bf(b[7]) << 16);
        *(uint4*)(Hh + (size_t)node * FEAT + l16 * 8) = o;
    }
}

// ---------------- pool: P[g] += G3[i] for batch[i]==g (sorted) ---------------
// 1563 blocks x 64 rows (R2's proven structure; R7's 512-block fused version
// was latency-starved at 77us). bf16 in, fp32 run-aggregated atomics out.
__global__ __launch_bounds__(128) void pool_kernel(const ushort16* __restrict__ H,
                                                   const int* __restrict__ batch,
                                                   float* __restrict__ P, int n) {
    int t = threadIdx.x;  // feature
    int i0 = blockIdx.x * 64;
    if (i0 >= n) return;
    int i1 = min(i0 + 64, n);
    float acc = 0.f;
    int g = batch[i0];
    for (int i = i0; i < i1; i++) {
        int b = batch[i];
        if (b != g) {
            atomicAdd(&P[(size_t)g * FEAT + t], acc);
            acc = 0.f;
            g = b;
        }
        uint32 u = (uint32)(unsigned short)H[(size_t)i * FEAT + t];
        acc += __uint_as_float(u << 16);
    }
    atomicAdd(&P[(size_t)g * FEAT + t], acc);
}

// ---------------- final tiny GEMM: out[g] = P[g] @ W2 (fp32) -----------------
__global__ __launch_bounds__(128) void pgemm_kernel(const float* __restrict__ P,
                                                    const float* __restrict__ W2,
                                                    float* __restrict__ out) {
    __shared__ float sP[FEAT];
    const int g = blockIdx.x;
    const int t = threadIdx.x;
    sP[t] = P[(size_t)g * FEAT + t];
    __syncthreads();
    float o = 0.f;
#pragma unroll 4
    for (int k = 0; k < FEAT; k++) o += sP[k] * W2[(size_t)k * FEAT + t];
    out[(size_t)g * FEAT + t] = o;
}

extern "C" void kernel_launch(void* const* d_in, const int* in_sizes, int n_in,
                              void* d_out, int out_size, void* d_ws, size_t ws_size,
                              hipStream_t stream) {
    const float* x = (const float*)d_in[0];
    const int* ei = (const int*)d_in[1];
    const int* batch = (const int*)d_in[2];
    const float* W0 = (const float*)d_in[3];
    const float* W1 = (const float*)d_in[4];
    const float* W2 = (const float*)d_in[5];
    float* out = (float*)d_out;

    const int N = in_sizes[0] / FEAT;  // 100000
    const int E = in_sizes[1] / 2;     // 640000
    const int G = out_size / FEAT;     // 512

    const int* rowI = ei;
    const int* colI = ei + E;

    char* ws = (char*)d_ws;
    auto take = [&](size_t bytes) {
        char* p = ws;
        ws += (bytes + 15) & ~(size_t)15;
        return p;
    };
    int* counts    = (int*)take((size_t)N * 4);
    int* off       = (int*)take((size_t)(N + 1) * 4);
    int* nxt       = (int*)take((size_t)N * 4);
    float* dinv    = (float*)take((size_t)N * 4);
    int* bsum      = (int*)take(128 * 4);
    uint64* erec   = (uint64*)take((size_t)E * 8);
    ushort16* W01t = (ushort16*)take((size_t)16384 * 2);
    float* Pbuf    = (float*)take((size_t)G * FEAT * 4);
    ushort16* Xh   = (ushort16*)take((size_t)N * FEAT * 2);
    ushort16* bufA = (ushort16*)take((size_t)N * FEAT * 2);
    ushort16* bufB = (ushort16*)take((size_t)N * FEAT * 2);

    const int nb = (N + 1023) / 1024;
    const int eb = (E + 255) / 256;

    // ---- zero counts + P, then fused pre-work (cvt_x + hist + W01) ----
    hipMemsetAsync(counts, 0, (size_t)N * 4, stream);
    hipMemsetAsync(Pbuf, 0, (size_t)G * FEAT * 4, stream);
    const int total8 = N * FEAT / 8;
    const int cvtBlocks = (total8 + 255) / 256;
    const int histBlocks = (E + 1023) / 1024;
    hydra_kernel<<<cvtBlocks + histBlocks + 64, 256, 0, stream>>>(
        x, Xh, colI, counts, W0, W1, W01t, cvtBlocks, histBlocks, total8, E);

    // ---- CSR build ----
    scan_part<<<nb, 256, 0, stream>>>(counts, bsum, N);
    scan_bsum<<<1, 128, 0, stream>>>(bsum, nb);
    scan_final<<<nb, 256, 0, stream>>>(counts, bsum, off, nxt, dinv, N);
    fill_kernel<<<eb, 256, 0, stream>>>(rowI, colI, dinv, nxt, erec, E);

    const int gatBlocks = (N + 3) / 4;

    // ---- H2 = A A X (W0 W1), leaky -> H3 ----
    gather_kernel<<<gatBlocks, 256, 0, stream>>>(off, (const uint2*)erec, dinv, Xh, bufA, N);
    gather_kernel<<<gatBlocks, 256, 0, stream>>>(off, (const uint2*)erec, dinv, bufA, bufB, N);
    gemm_mfma<<<1024, 256, 0, stream>>>(bufB, W01t, bufA, N, 1);  // leaky fused
    // ---- G3 = A H3 ----
    gather_kernel<<<gatBlocks, 256, 0, stream>>>(off, (const uint2*)erec, dinv, bufA, bufB, N);
    // ---- out = pool(G3) @ W2 ----
    pool_kernel<<<(N + 63) / 64, 128, 0, stream>>>(bufB, batch, Pbuf, N);
    pgemm_kernel<<<G, 128, 0, stream>>>(Pbuf, W2, out);
}

// Round 9
// 361.068 us; speedup vs baseline: 1.1231x; 1.0348x over previous
//
#include <hip/hip_runtime.h>
#include <hip/hip_bf16.h>

#define FEAT 128

typedef unsigned int uint32;
typedef unsigned long long uint64;
typedef unsigned short ushort16;
typedef __attribute__((ext_vector_type(8))) short short8;
typedef __attribute__((ext_vector_type(4))) float v4f;
typedef __attribute__((ext_vector_type(2))) float f32x2;

// ---- bf16 helpers (RNE round; bf16->f32 is exact shift) ---------------------
__device__ __forceinline__ ushort16 f2bf(float f) {
    uint32 u = __float_as_uint(f);
    u += 0x7fffu + ((u >> 16) & 1u);
    return (ushort16)(u >> 16);
}
__device__ __forceinline__ float bflo(uint32 u) { return __uint_as_float(u << 16); }
__device__ __forceinline__ float bfhi(uint32 u) { return __uint_as_float(u & 0xffff0000u); }
__device__ __forceinline__ f32x2 up2(uint32 u) { return (f32x2){bflo(u), bfhi(u)}; }

// ---------------- hydra: cvt_x + hist + W01=W0@W1 + zero(P) ------------------
// blocks [0, CB): convert x fp32 -> bf16, 8 elems/thread
// blocks [CB, CB+HB): histogram of col (4 edges/thread)
// blocks [CB+HB, CB+HB+64): W01t[n][k] = sum_j W0[k][j]*W1[j][n]
// blocks [CB+HB+64, CB+HB+96): zero the 256KB pool accumulator
__global__ __launch_bounds__(256) void hydra_kernel(const float* __restrict__ x,
                                                    ushort16* __restrict__ Xh,
                                                    const int* __restrict__ col,
                                                    int* __restrict__ counts,
                                                    const float* __restrict__ W0,
                                                    const float* __restrict__ W1,
                                                    ushort16* __restrict__ W01t,
                                                    float* __restrict__ Pbuf,
                                                    int cvtBlocks, int histBlocks,
                                                    int total8, int E) {
    int b = blockIdx.x;
    int t = threadIdx.x;
    if (b < cvtBlocks) {
        int id = b * 256 + t;
        if (id < total8) {
            const float4 v0 = *(const float4*)(x + (size_t)id * 8);
            const float4 v1 = *(const float4*)(x + (size_t)id * 8 + 4);
            uint4 o;
            o.x = (uint32)f2bf(v0.x) | ((uint32)f2bf(v0.y) << 16);
            o.y = (uint32)f2bf(v0.z) | ((uint32)f2bf(v0.w) << 16);
            o.z = (uint32)f2bf(v1.x) | ((uint32)f2bf(v1.y) << 16);
            o.w = (uint32)f2bf(v1.z) | ((uint32)f2bf(v1.w) << 16);
            *(uint4*)(Xh + (size_t)id * 8) = o;
        }
    } else if (b < cvtBlocks + histBlocks) {
        int id = (b - cvtBlocks) * 256 + t;
        if (id * 4 + 3 < E) {
            int4 c4 = *(const int4*)(col + id * 4);
            atomicAdd(&counts[c4.x], 1);
            atomicAdd(&counts[c4.y], 1);
            atomicAdd(&counts[c4.z], 1);
            atomicAdd(&counts[c4.w], 1);
        } else {
            for (int e = id * 4; e < E; e++) atomicAdd(&counts[col[e]], 1);
        }
    } else if (b < cvtBlocks + histBlocks + 64) {
        __shared__ float sW0[2][FEAT];
        int wb = b - cvtBlocks - histBlocks;  // [0, 64)
        int lk = t >> 7;                      // which of the 2 k-rows
        int ncol = t & 127;
        int k = wb * 2 + lk;
        sW0[lk][ncol] = W0[(size_t)k * FEAT + ncol];
        __syncthreads();
        float acc = 0.f;
#pragma unroll 4
        for (int j = 0; j < FEAT; j++)
            acc += sW0[lk][j] * W1[(size_t)j * FEAT + ncol];  // coalesced across lanes
        W01t[(size_t)ncol * FEAT + k] = f2bf(acc);  // [n][k], transposed for MFMA
    } else {
        int zb = b - cvtBlocks - histBlocks - 64;  // [0, 32): 512*128 floats
        float4 z = make_float4(0.f, 0.f, 0.f, 0.f);
        float* p = Pbuf + (size_t)zb * 2048 + t * 8;
        *(float4*)p = z;
        *(float4*)(p + 4) = z;
    }
}

// ---------------- scan step 1: per-1024-chunk sums ---------------------------
__global__ __launch_bounds__(256) void scan_part(const int* __restrict__ counts,
                                                 int* __restrict__ bsum, int n) {
    __shared__ int s[256];
    int base = blockIdx.x * 1024;
    int t = threadIdx.x;
    int v = 0;
#pragma unroll
    for (int i = 0; i < 4; i++) {
        int idx = base + t * 4 + i;
        if (idx < n) v += counts[idx];
    }
    s[t] = v;
    __syncthreads();
    for (int o = 128; o > 0; o >>= 1) {
        if (t < o) s[t] += s[t + o];
        __syncthreads();
    }
    if (t == 0) bsum[blockIdx.x] = s[0];
}

// ---------------- scan step 2 (merged): offsets + next[] + dinv --------------
// Each block redundantly prefix-sums the raw bsum[] (nb<=128 entries) instead
// of a separate scan_bsum launch.
__global__ __launch_bounds__(256) void scan_final(const int* __restrict__ counts,
                                                  const int* __restrict__ bsum,
                                                  int* __restrict__ off, int* __restrict__ nxt,
                                                  float* __restrict__ dinv, int n, int nb) {
    __shared__ int s[256];
    __shared__ int sb[128];
    int base = blockIdx.x * 1024;
    int t = threadIdx.x;
    if (t < nb) sb[t] = bsum[t];
    int c[4];
    int sum = 0;
#pragma unroll
    for (int i = 0; i < 4; i++) {
        int idx = base + t * 4 + i;
        c[i] = (idx < n) ? counts[idx] : 0;
        sum += c[i];
    }
    int v0 = sum;
    s[t] = sum;
    __syncthreads();
    for (int o = 1; o < 256; o <<= 1) {
        int v = (t >= o) ? s[t - o] : 0;
        __syncthreads();
        s[t] += v;
        __syncthreads();
    }
    int blockBase = 0;
    for (int j = 0; j < blockIdx.x; j++) blockBase += sb[j];  // LDS broadcast walk
    int excl = s[t] - v0 + blockBase;
#pragma unroll
    for (int i = 0; i < 4; i++) {
        int idx = base + t * 4 + i;
        if (idx < n) {
            off[idx] = excl;
            nxt[idx] = excl;
            dinv[idx] = rsqrtf((float)(c[i] + 1));  // +1 = self loop
        }
        excl += c[i];
    }
    if (blockIdx.x == gridDim.x - 1 && t == 255) off[n] = excl;  // == E
}

// ---------------- CSR fill: 4B src records (R8: 8B records -> 44.7MB of ------
// partial-line HBM write thrash; halving record size halves it; gather
// recomputes dinv[src] from the L2-resident 400KB table instead) -------------
__global__ void fill_kernel(const int* __restrict__ row, const int* __restrict__ col,
                            int* __restrict__ nxt,
                            int* __restrict__ srcArr, int E) {
    int e = blockIdx.x * 256 + threadIdx.x;
    if (e < E) {
        int c = col[e], r = row[e];
        int p = atomicAdd(&nxt[c], 1);
        __builtin_nontemporal_store(r, &srcArr[p]);
    }
}

// ---------------- bf16 MFMA GEMM: Ch = bf16(leaky?(Ah @ W)), W transposed ----
// Half-W-per-wave register-resident (R6 design, frozen). OPERAND SWAP
// (verified R4): mfma(Wfrag, Afrag) -> lane holds 4 consecutive W-cols of
// node row l16 -> direct 8B packed stores.
__global__ __launch_bounds__(256) void gemm_mfma(const ushort16* __restrict__ A,
                                                 const ushort16* __restrict__ Wt,
                                                 ushort16* __restrict__ Ch, int n,
                                                 int leaky) {
    const int t = threadIdx.x;
    const int w = t >> 6;
    const int lane = t & 63;
    const int quad = lane >> 4;
    const int l16 = lane & 15;
    const int colBase = (w & 1) * 64;

    short8 wf[4][4];
#pragma unroll
    for (int ct = 0; ct < 4; ct++) {
        const ushort16* wp = Wt + (size_t)(colBase + ct * 16 + l16) * FEAT + quad * 8;
#pragma unroll
        for (int ks = 0; ks < 4; ks++) wf[ct][ks] = *(const short8*)(wp + ks * 32);
    }

    const int nTiles = (n + 15) >> 4;
    const int tStride = gridDim.x * 2;
    int tile = blockIdx.x * 2 + (w >> 1);
    if (tile >= nTiles) return;

    auto loadA = [&](int tl, short8 (&a)[4]) {
        const int row = tl * 16 + l16;
        if (row < n) {
            const ushort16* ap = A + (size_t)row * FEAT + quad * 8;
#pragma unroll
            for (int ks = 0; ks < 4; ks++) a[ks] = *(const short8*)(ap + ks * 32);
        } else {
#pragma unroll
            for (int ks = 0; ks < 4; ks++) a[ks] = (short8)0;
        }
    };

    short8 aCur[4];
    loadA(tile, aCur);

    while (tile < nTiles) {
        const int nextTile = tile + tStride;
        short8 aNxt[4];
        if (nextTile < nTiles) loadA(nextTile, aNxt);

        v4f acc[4];
#pragma unroll
        for (int ct = 0; ct < 4; ct++) acc[ct] = (v4f)0.f;
#pragma unroll
        for (int ct = 0; ct < 4; ct++)
#pragma unroll
            for (int ks = 0; ks < 4; ks++)
                acc[ct] = __builtin_amdgcn_mfma_f32_16x16x32_bf16(wf[ct][ks], aCur[ks], acc[ct], 0, 0, 0);

        const int row = tile * 16 + l16;
        if (row < n) {
#pragma unroll
            for (int ct = 0; ct < 4; ct++) {
                float p0 = acc[ct][0], p1 = acc[ct][1], p2 = acc[ct][2], p3 = acc[ct][3];
                if (leaky) {
                    p0 = (p0 >= 0.f) ? p0 : 0.01f * p0;
                    p1 = (p1 >= 0.f) ? p1 : 0.01f * p1;
                    p2 = (p2 >= 0.f) ? p2 : 0.01f * p2;
                    p3 = (p3 >= 0.f) ? p3 : 0.01f * p3;
                }
                uint2 o;
                o.x = (uint32)f2bf(p0) | ((uint32)f2bf(p1) << 16);
                o.y = (uint32)f2bf(p2) | ((uint32)f2bf(p3) << 16);
                *(uint2*)(Ch + (size_t)row * FEAT + colBase + ct * 16 + quad * 4) = o;
            }
        }

        tile = nextTile;
#pragma unroll
        for (int ks = 0; ks < 4; ks++) aCur[ks] = aNxt[ks];
    }
}

// ---------------- gather-propagate over bf16 table ---------------------------
// H[c] = dinv[c]^2*T[c] + sum_e dinv[c]*dinv[src_e]*T[src_e]; bf16 out.
// 4 edge-groups x 16 lanes x 16B, unroll-2 (structural ~49us: L2-miss traffic
// at L3 random-access rate). dinv[src] loaded per edge (L2-resident 400KB;
// issues in parallel with the row load -- both depend only on src).
__global__ __launch_bounds__(256) void gather_kernel(const int* __restrict__ off,
                                                     const int* __restrict__ srcArr,
                                                     const float* __restrict__ dinv,
                                                     const ushort16* __restrict__ XWh,
                                                     ushort16* __restrict__ Hh, int n) {
    int node = blockIdx.x * 4 + (threadIdx.x >> 6);
    if (node >= n) return;
    int lane = threadIdx.x & 63;
    int grp = lane >> 4;
    int l16 = lane & 15;
    float dc = dinv[node];
    const uint4* table = (const uint4*)XWh;

    f32x2 acc[4];
    if (grp == 0) {  // self-loop term
        uint4 v = table[(size_t)node * 16 + l16];
        f32x2 w0 = (f32x2){dc * dc, dc * dc};
        acc[0] = w0 * up2(v.x);
        acc[1] = w0 * up2(v.y);
        acc[2] = w0 * up2(v.z);
        acc[3] = w0 * up2(v.w);
    } else {
#pragma unroll
        for (int j = 0; j < 4; j++) acc[j] = (f32x2){0.f, 0.f};
    }

    int s = off[node], e = off[node + 1];
    int i = s + grp;
    for (; i + 4 < e; i += 8) {
        int r0 = srcArr[i];
        int r1 = srcArr[i + 4];
        uint4 u0 = table[(size_t)r0 * 16 + l16];
        uint4 u1 = table[(size_t)r1 * 16 + l16];
        float f0 = dc * dinv[r0];
        float f1 = dc * dinv[r1];
        f32x2 n0 = (f32x2){f0, f0};
        f32x2 n1 = (f32x2){f1, f1};
        acc[0] += n0 * up2(u0.x);
        acc[1] += n0 * up2(u0.y);
        acc[2] += n0 * up2(u0.z);
        acc[3] += n0 * up2(u0.w);
        acc[0] += n1 * up2(u1.x);
        acc[1] += n1 * up2(u1.y);
        acc[2] += n1 * up2(u1.z);
        acc[3] += n1 * up2(u1.w);
    }
    if (i < e) {
        int r0 = srcArr[i];
        uint4 u0 = table[(size_t)r0 * 16 + l16];
        float f0 = dc * dinv[r0];
        f32x2 n0 = (f32x2){f0, f0};
        acc[0] += n0 * up2(u0.x);
        acc[1] += n0 * up2(u0.y);
        acc[2] += n0 * up2(u0.z);
        acc[3] += n0 * up2(u0.w);
    }

    float b[8] = {acc[0].x, acc[0].y, acc[1].x, acc[1].y,
                  acc[2].x, acc[2].y, acc[3].x, acc[3].y};
#pragma unroll
    for (int j = 0; j < 8; j++) {
        b[j] += __shfl_xor(b[j], 16);
        b[j] += __shfl_xor(b[j], 32);
    }

    if (grp == 0) {
        uint4 o;
        o.x = (uint32)f2bf(b[0]) | ((uint32)f2bf(b[1]) << 16);
        o.y = (uint32)f2bf(b[2]) | ((uint32)f2bf(b[3]) << 16);
        o.z = (uint32)f2bf(b[4]) | ((uint32)f2bf(b[5]) << 16);
        o.w = (uint32)f2bf(b[6]) | ((uint32)f2bf(b[7]) << 16);
        *(uint4*)(Hh + (size_t)node * FEAT + l16 * 8) = o;
    }
}

// ---------------- pool: P[g] += G3[i] for batch[i]==g (sorted) ---------------
// 1563 blocks x 64 rows; run-aggregated fp32 atomics (proven R2/R8 structure).
__global__ __launch_bounds__(128) void pool_kernel(const ushort16* __restrict__ H,
                                                   const int* __restrict__ batch,
                                                   float* __restrict__ P, int n) {
    int t = threadIdx.x;  // feature
    int i0 = blockIdx.x * 64;
    if (i0 >= n) return;
    int i1 = min(i0 + 64, n);
    float acc = 0.f;
    int g = batch[i0];
    for (int i = i0; i < i1; i++) {
        int b = batch[i];
        if (b != g) {
            atomicAdd(&P[(size_t)g * FEAT + t], acc);
            acc = 0.f;
            g = b;
        }
        uint32 u = (uint32)(unsigned short)H[(size_t)i * FEAT + t];
        acc += __uint_as_float(u << 16);
    }
    atomicAdd(&P[(size_t)g * FEAT + t], acc);
}

// ---------------- final tiny GEMM: out[g] = P[g] @ W2 (fp32) -----------------
__global__ __launch_bounds__(128) void pgemm_kernel(const float* __restrict__ P,
                                                    const float* __restrict__ W2,
                                                    float* __restrict__ out) {
    __shared__ float sP[FEAT];
    const int g = blockIdx.x;
    const int t = threadIdx.x;
    sP[t] = P[(size_t)g * FEAT + t];
    __syncthreads();
    float o = 0.f;
#pragma unroll 4
    for (int k = 0; k < FEAT; k++) o += sP[k] * W2[(size_t)k * FEAT + t];
    out[(size_t)g * FEAT + t] = o;
}

extern "C" void kernel_launch(void* const* d_in, const int* in_sizes, int n_in,
                              void* d_out, int out_size, void* d_ws, size_t ws_size,
                              hipStream_t stream) {
    const float* x = (const float*)d_in[0];
    const int* ei = (const int*)d_in[1];
    const int* batch = (const int*)d_in[2];
    const float* W0 = (const float*)d_in[3];
    const float* W1 = (const float*)d_in[4];
    const float* W2 = (const float*)d_in[5];
    float* out = (float*)d_out;

    const int N = in_sizes[0] / FEAT;  // 100000
    const int E = in_sizes[1] / 2;     // 640000
    const int G = out_size / FEAT;     // 512

    const int* rowI = ei;
    const int* colI = ei + E;

    char* ws = (char*)d_ws;
    auto take = [&](size_t bytes) {
        char* p = ws;
        ws += (bytes + 15) & ~(size_t)15;
        return p;
    };
    int* counts    = (int*)take((size_t)N * 4);
    int* off       = (int*)take((size_t)(N + 1) * 4);
    int* nxt       = (int*)take((size_t)N * 4);
    float* dinv    = (float*)take((size_t)N * 4);
    int* bsum      = (int*)take(128 * 4);
    int* srcArr    = (int*)take((size_t)E * 4);
    ushort16* W01t = (ushort16*)take((size_t)16384 * 2);
    float* Pbuf    = (float*)take((size_t)G * FEAT * 4);
    ushort16* Xh   = (ushort16*)take((size_t)N * FEAT * 2);
    ushort16* bufA = (ushort16*)take((size_t)N * FEAT * 2);
    ushort16* bufB = (ushort16*)take((size_t)N * FEAT * 2);

    const int nb = (N + 1023) / 1024;  // 98
    const int eb = (E + 255) / 256;

    // ---- zero counts, then fused pre-work (cvt_x + hist + W01 + zero P) ----
    hipMemsetAsync(counts, 0, (size_t)N * 4, stream);
    const int total8 = N * FEAT / 8;
    const int cvtBlocks = (total8 + 255) / 256;
    const int histBlocks = (E + 1023) / 1024;
    hydra_kernel<<<cvtBlocks + histBlocks + 64 + 32, 256, 0, stream>>>(
        x, Xh, colI, counts, W0, W1, W01t, Pbuf, cvtBlocks, histBlocks, total8, E);

    // ---- CSR build (2-kernel scan) ----
    scan_part<<<nb, 256, 0, stream>>>(counts, bsum, N);
    scan_final<<<nb, 256, 0, stream>>>(counts, bsum, off, nxt, dinv, N, nb);
    fill_kernel<<<eb, 256, 0, stream>>>(rowI, colI, nxt, srcArr, E);

    const int gatBlocks = (N + 3) / 4;

    // ---- H2 = A A X (W0 W1), leaky -> H3 ----
    gather_kernel<<<gatBlocks, 256, 0, stream>>>(off, srcArr, dinv, Xh, bufA, N);
    gather_kernel<<<gatBlocks, 256, 0, stream>>>(off, srcArr, dinv, bufA, bufB, N);
    gemm_mfma<<<1024, 256, 0, stream>>>(bufB, W01t, bufA, N, 1);  // leaky fused
    // ---- G3 = A H3 ----
    gather_kernel<<<gatBlocks, 256, 0, stream>>>(off, srcArr, dinv, bufA, bufB, N);
    // ---- out = pool(G3) @ W2 ----
    pool_kernel<<<(N + 63) / 64, 128, 0, stream>>>(bufB, batch, Pbuf, N);
    pgemm_kernel<<<G, 128, 0, stream>>>(Pbuf, W2, out);
}